// Round 5
// baseline (1076.604 us; speedup 1.0000x reference)
//
#include <hip/hip_runtime.h>
#include <hip/hip_cooperative_groups.h>

namespace cg = cooperative_groups;

#define NS 50000
#define NE 800000
#define XD 64
#define HD 64
#define YD 32

#define NTHR 256
#define NBLK 1024
#define FILL_BLKS 640
#define SCAN_CHUNK 256
#define SCAN_NBLK ((NS + SCAN_CHUNK - 1) / SCAN_CHUNK)  // 196

// ---- bf16 helpers (round-to-nearest-even pack, cheap unpack) ----
__device__ __forceinline__ unsigned f2b(float f) {
    union { float f; unsigned u; } c; c.f = f;
    return (c.u + 0x7fffu + ((c.u >> 16) & 1u)) >> 16;
}
__device__ __forceinline__ float blo(unsigned u) {
    union { unsigned u; float f; } c; c.u = u << 16; return c.f;
}
__device__ __forceinline__ float bhi(unsigned u) {
    union { unsigned u; float f; } c; c.u = u & 0xffff0000u; return c.f;
}

// ============================================================================
// Fused cooperative kernel: all stages, grid.sync() between dependent stages.
// ============================================================================
__global__ __launch_bounds__(NTHR, 4) void k_all(
    const float* __restrict__ x, const float* __restrict__ W1,
    const float* __restrict__ b1, const float* __restrict__ W2,
    const float* __restrict__ b2, const int* __restrict__ src,
    const int* __restrict__ dst, int* __restrict__ degi,
    int* __restrict__ rowptr, int* __restrict__ cursor,
    int* __restrict__ partials, int* __restrict__ blockoff,
    unsigned short* __restrict__ csr, float* __restrict__ dinv,
    unsigned* __restrict__ G1h, unsigned* __restrict__ G2h,
    float* __restrict__ O2, float* __restrict__ out)
{
    cg::grid_group grid = cg::this_grid();
    __shared__ float lds_w[XD * HD];   // 16 KB: W1 in S5, W2 in S6
    __shared__ float lds_b[HD];
    __shared__ float lds_h[4][HD];
    __shared__ int   lds_i[NTHR];

    const int tid = blockIdx.x * NTHR + threadIdx.x;
    const int NT  = gridDim.x * NTHR;

    // ---- S0: zero degree array ----
    for (int i = tid; i < NS; i += NT) degi[i] = 0;
    grid.sync();

    // ---- S1: in-degree histogram ----
    for (int e = tid; e < NE; e += NT)
        atomicAdd(&degi[__builtin_nontemporal_load(dst + e)], 1);
    grid.sync();

    // ---- S2: per-chunk partial sums (196 blocks) ----
    if (blockIdx.x < SCAN_NBLK) {
        int t = threadIdx.x;
        int i = blockIdx.x * SCAN_CHUNK + t;
        lds_i[t] = (i < NS) ? degi[i] : 0;
        __syncthreads();
        for (int off = 128; off > 0; off >>= 1) {
            if (t < off) lds_i[t] += lds_i[t + off];
            __syncthreads();
        }
        if (t == 0) partials[blockIdx.x] = lds_i[0];
    }
    grid.sync();

    // ---- S3: scan the partials (block 0 only) ----
    if (blockIdx.x == 0) {
        int t = threadIdx.x;
        int v = (t < SCAN_NBLK) ? partials[t] : 0;
        lds_i[t] = v;
        __syncthreads();
        int val = v;
        for (int off = 1; off < 256; off <<= 1) {
            int other = (t >= off) ? lds_i[t - off] : 0;
            __syncthreads();
            val += other;
            lds_i[t] = val;
            __syncthreads();
        }
        if (t < SCAN_NBLK) blockoff[t] = val - v;  // exclusive
    }
    grid.sync();

    // ---- S4: apply scan -> rowptr/cursor/dinv ----
    if (blockIdx.x < SCAN_NBLK) {
        int t = threadIdx.x;
        int i = blockIdx.x * SCAN_CHUNK + t;
        int dg = (i < NS) ? degi[i] : 0;
        lds_i[t] = dg;
        __syncthreads();
        int val = dg;
        for (int off = 1; off < 256; off <<= 1) {
            int other = (t >= off) ? lds_i[t - off] : 0;
            __syncthreads();
            val += other;
            lds_i[t] = val;
            __syncthreads();
        }
        if (i < NS) {
            int ex = blockoff[blockIdx.x] + val - dg;
            rowptr[i] = ex;
            cursor[i] = ex;
            dinv[i] = rsqrtf((float)dg + 1.0f);  // +1 = self loop
        }
        if (blockIdx.x == 0 && t == 0) rowptr[NS] = NE;
    }
    grid.sync();

    // ---- S5: CSR fill (blocks [0,FILL_BLKS)) || xw1 transform (rest) ----
    if (blockIdx.x < FILL_BLKS) {
        int ft = blockIdx.x * NTHR + threadIdx.x;
        for (int e = ft; e < NE; e += FILL_BLKS * NTHR) {
            int d = __builtin_nontemporal_load(dst + e);
            int s = __builtin_nontemporal_load(src + e);
            int pos = atomicAdd(&cursor[d], 1);
            csr[pos] = (unsigned short)s;
        }
    } else {
        for (int i = threadIdx.x; i < XD * HD; i += NTHR) lds_w[i] = W1[i];
        __syncthreads();
        int xt = (blockIdx.x - FILL_BLKS) * NTHR + threadIdx.x;
        for (int s = xt; s < NS; s += (NBLK - FILL_BLKS) * NTHR) {
            float4 acc[HD / 4];
#pragma unroll
            for (int i = 0; i < HD / 4; ++i) acc[i] = make_float4(0.f, 0.f, 0.f, 0.f);
            for (int xf = 0; xf < XD; ++xf) {
                float xv = __builtin_nontemporal_load(&x[(size_t)xf * NS + s]);
                const float4* wr = (const float4*)&lds_w[xf * HD];
#pragma unroll
                for (int i = 0; i < HD / 4; ++i) {
                    float4 wv = wr[i];
                    acc[i].x += xv * wv.x; acc[i].y += xv * wv.y;
                    acc[i].z += xv * wv.z; acc[i].w += xv * wv.w;
                }
            }
            float dv = dinv[s];
            unsigned pk[HD / 2];
#pragma unroll
            for (int i = 0; i < HD / 4; ++i) {
                pk[2 * i]     = f2b(dv * acc[i].x) | (f2b(dv * acc[i].y) << 16);
                pk[2 * i + 1] = f2b(dv * acc[i].z) | (f2b(dv * acc[i].w) << 16);
            }
            uint4* o = (uint4*)&G1h[(size_t)s * (HD / 2)];
#pragma unroll
            for (int i = 0; i < HD / 8; ++i) o[i] = ((uint4*)pk)[i];
        }
    }
    grid.sync();

    // ---- S6: fused gather-1 + ReLU + layer-2 matvec ----
    for (int i = threadIdx.x; i < HD * YD; i += NTHR) lds_w[i] = W2[i];
    if (threadIdx.x < HD) lds_b[threadIdx.x] = b1[threadIdx.x];
    __syncthreads();
    {
        int wv = threadIdx.x >> 6, lane = threadIdx.x & 63;
        int half = lane >> 5, fp = lane & 31;
        int wgid = blockIdx.x * 4 + wv;
        int nw = NT >> 6;  // 4096 waves
        for (int node = wgid; node < NS; node += nw) {
            int beg = rowptr[node], end = rowptr[node + 1];
            float ax = 0.f, ay = 0.f;
            for (int base = beg; base < end; base += 64) {
                int cnt = min(end - base, 64);
                int idx = (lane < cnt) ? (int)__builtin_nontemporal_load(csr + base + lane) : 0;
                int it = (cnt + 1) >> 1;
#pragma unroll 4
                for (int j = 0; j < it; ++j) {
                    int nsel = 2 * j + half;
                    int s = __shfl(idx, min(nsel, cnt - 1));
                    unsigned u = G1h[(size_t)s * 32 + fp];   // 4B/lane, 128B/team
                    float m = (nsel < cnt) ? 1.f : 0.f;
                    ax = fmaf(m, blo(u), ax);
                    ay = fmaf(m, bhi(u), ay);
                }
            }
            ax += __shfl_xor(ax, 32);
            ay += __shfl_xor(ay, 32);
            unsigned us = G1h[(size_t)node * 32 + fp];       // self loop
            float dv = dinv[node];
            float h0 = fmaxf(fmaf(dv, ax + blo(us), lds_b[2 * fp]), 0.f);
            float h1 = fmaxf(fmaf(dv, ay + bhi(us), lds_b[2 * fp + 1]), 0.f);
            if (half == 0) { lds_h[wv][2 * fp] = h0; lds_h[wv][2 * fp + 1] = h1; }
            __syncthreads();
            float p = 0.f;
            const float* hh = lds_h[wv];
#pragma unroll
            for (int f = 0; f < 32; ++f)
                p = fmaf(hh[half * 32 + f], lds_w[(half * 32 + f) * YD + fp], p);
            p += __shfl_xor(p, 32);
            p *= dv;
            float pn = __shfl_xor(p, 1);
            if (half == 0 && (fp & 1) == 0)
                G2h[(size_t)node * 16 + (fp >> 1)] = f2b(p) | (f2b(pn) << 16);
        }
    }
    grid.sync();

    // ---- S7: gather layer 2 (4x16-lane teams per wave) ----
    {
        int wv = threadIdx.x >> 6, lane = threadIdx.x & 63;
        int q = lane >> 4, fp = lane & 15;
        int wgid = blockIdx.x * 4 + wv;
        int nw = NT >> 6;
        for (int node = wgid; node < NS; node += nw) {
            int beg = rowptr[node], end = rowptr[node + 1];
            float ax = 0.f, ay = 0.f;
            for (int base = beg; base < end; base += 64) {
                int cnt = min(end - base, 64);
                int idx = (lane < cnt) ? (int)__builtin_nontemporal_load(csr + base + lane) : 0;
                int it = (cnt + 3) >> 2;
#pragma unroll 4
                for (int j = 0; j < it; ++j) {
                    int nsel = 4 * j + q;
                    int s = __shfl(idx, min(nsel, cnt - 1));
                    unsigned u = G2h[(size_t)s * 16 + fp];   // 4B/lane, 64B/team
                    float m = (nsel < cnt) ? 1.f : 0.f;
                    ax = fmaf(m, blo(u), ax);
                    ay = fmaf(m, bhi(u), ay);
                }
            }
            ax += __shfl_xor(ax, 16); ay += __shfl_xor(ay, 16);
            ax += __shfl_xor(ax, 32); ay += __shfl_xor(ay, 32);
            unsigned us = G2h[(size_t)node * 16 + fp];
            float dv = dinv[node];
            if (q == 0) {
                float2* o = (float2*)O2;
                o[(size_t)node * 16 + fp] =
                    make_float2(dv * (ax + blo(us)), dv * (ay + bhi(us)));
            }
        }
    }
    grid.sync();

    // ---- S8: epilogue + transpose ----
    for (int s = tid; s < NS; s += NT) {
#pragma unroll
        for (int o = 0; o < YD; ++o)
            out[(size_t)o * NS + s] = O2[(size_t)s * YD + o] + b2[o];
    }
}

// ============================================================================
// Fallback path (R3 kernels) — used only if cooperative launch fails.
// ============================================================================
__global__ void k_degi(const int* __restrict__ dst, int* __restrict__ deg) {
    int e = blockIdx.x * blockDim.x + threadIdx.x;
    if (e < NE) atomicAdd(&deg[__builtin_nontemporal_load(dst + e)], 1);
}

__global__ __launch_bounds__(256) void k_part(const int* __restrict__ deg,
                                              int* __restrict__ partials) {
    __shared__ int red[256];
    int t = threadIdx.x;
    int i = blockIdx.x * SCAN_CHUNK + t;
    red[t] = (i < NS) ? deg[i] : 0;
    __syncthreads();
    for (int off = 128; off > 0; off >>= 1) {
        if (t < off) red[t] += red[t + off];
        __syncthreads();
    }
    if (t == 0) partials[blockIdx.x] = red[0];
}

__global__ __launch_bounds__(256) void k_scan2(const int* __restrict__ partials,
                                               int* __restrict__ blockoff) {
    __shared__ int sm[256];
    int t = threadIdx.x;
    int v = (t < SCAN_NBLK) ? partials[t] : 0;
    sm[t] = v;
    __syncthreads();
    int val = v;
    for (int off = 1; off < 256; off <<= 1) {
        int other = (t >= off) ? sm[t - off] : 0;
        __syncthreads();
        val += other;
        sm[t] = val;
        __syncthreads();
    }
    if (t < SCAN_NBLK) blockoff[t] = val - v;
}

__global__ __launch_bounds__(256) void k_apply(const int* __restrict__ deg,
                                               const int* __restrict__ blockoff,
                                               int* __restrict__ rowptr,
                                               int* __restrict__ cursor,
                                               float* __restrict__ dinv) {
    __shared__ int sm[256];
    int t = threadIdx.x;
    int i = blockIdx.x * SCAN_CHUNK + t;
    int dg = (i < NS) ? deg[i] : 0;
    sm[t] = dg;
    __syncthreads();
    int val = dg;
    for (int off = 1; off < 256; off <<= 1) {
        int other = (t >= off) ? sm[t - off] : 0;
        __syncthreads();
        val += other;
        sm[t] = val;
        __syncthreads();
    }
    if (i < NS) {
        int ex = blockoff[blockIdx.x] + val - dg;
        rowptr[i] = ex;
        cursor[i] = ex;
        dinv[i] = rsqrtf((float)dg + 1.0f);
    }
    if (blockIdx.x == 0 && t == 0) rowptr[NS] = NE;
}

__global__ void k_fill(const int* __restrict__ src, const int* __restrict__ dst,
                       int* __restrict__ cursor, unsigned short* __restrict__ csr) {
    int e = blockIdx.x * blockDim.x + threadIdx.x;
    if (e < NE) {
        int d = __builtin_nontemporal_load(dst + e);
        int s = __builtin_nontemporal_load(src + e);
        int pos = atomicAdd(&cursor[d], 1);
        csr[pos] = (unsigned short)s;
    }
}

__global__ __launch_bounds__(256) void k_xw1(const float* __restrict__ x,
                                             const float* __restrict__ W1,
                                             const float* __restrict__ dinv,
                                             unsigned* __restrict__ G1h) {
    __shared__ float w[XD * HD];
    for (int i = threadIdx.x; i < XD * HD; i += 256) w[i] = W1[i];
    __syncthreads();
    int s = blockIdx.x * 256 + threadIdx.x;
    if (s >= NS) return;
    float4 acc[HD / 4];
#pragma unroll
    for (int i = 0; i < HD / 4; ++i) acc[i] = make_float4(0.f, 0.f, 0.f, 0.f);
    for (int xf = 0; xf < XD; ++xf) {
        float xv = __builtin_nontemporal_load(&x[(size_t)xf * NS + s]);
        const float4* wr = (const float4*)&w[xf * HD];
#pragma unroll
        for (int i = 0; i < HD / 4; ++i) {
            float4 wv = wr[i];
            acc[i].x += xv * wv.x; acc[i].y += xv * wv.y;
            acc[i].z += xv * wv.z; acc[i].w += xv * wv.w;
        }
    }
    float dv = dinv[s];
    unsigned pk[HD / 2];
#pragma unroll
    for (int i = 0; i < HD / 4; ++i) {
        pk[2 * i]     = f2b(dv * acc[i].x) | (f2b(dv * acc[i].y) << 16);
        pk[2 * i + 1] = f2b(dv * acc[i].z) | (f2b(dv * acc[i].w) << 16);
    }
    uint4* o = (uint4*)&G1h[(size_t)s * (HD / 2)];
#pragma unroll
    for (int i = 0; i < HD / 8; ++i) o[i] = ((uint4*)pk)[i];
}

__global__ __launch_bounds__(256) void k_g1l2(const int* __restrict__ rowptr,
                                              const unsigned short* __restrict__ csr,
                                              const unsigned* __restrict__ G1h,
                                              const float* __restrict__ dinv,
                                              const float* __restrict__ b1,
                                              const float* __restrict__ W2,
                                              unsigned* __restrict__ G2h) {
    __shared__ float w2[HD * YD];
    __shared__ float bsh[HD];
    __shared__ float hsh[4][HD];
    for (int i = threadIdx.x; i < HD * YD; i += 256) w2[i] = W2[i];
    if (threadIdx.x < HD) bsh[threadIdx.x] = b1[threadIdx.x];
    __syncthreads();
    int wv = threadIdx.x >> 6, lane = threadIdx.x & 63;
    int node = blockIdx.x * 4 + wv;
    int half = lane >> 5, fp = lane & 31;
    int beg = rowptr[node], end = rowptr[node + 1];
    float ax = 0.f, ay = 0.f;
    for (int base = beg; base < end; base += 64) {
        int cnt = min(end - base, 64);
        int idx = (lane < cnt) ? (int)__builtin_nontemporal_load(csr + base + lane) : 0;
        int it = (cnt + 1) >> 1;
#pragma unroll 4
        for (int j = 0; j < it; ++j) {
            int nsel = 2 * j + half;
            int s = __shfl(idx, min(nsel, cnt - 1));
            unsigned u = G1h[(size_t)s * 32 + fp];
            float m = (nsel < cnt) ? 1.f : 0.f;
            ax = fmaf(m, blo(u), ax);
            ay = fmaf(m, bhi(u), ay);
        }
    }
    ax += __shfl_xor(ax, 32);
    ay += __shfl_xor(ay, 32);
    unsigned us = G1h[(size_t)node * 32 + fp];
    float dv = dinv[node];
    float h0 = fmaxf(fmaf(dv, ax + blo(us), bsh[2 * fp]), 0.f);
    float h1 = fmaxf(fmaf(dv, ay + bhi(us), bsh[2 * fp + 1]), 0.f);
    if (half == 0) { hsh[wv][2 * fp] = h0; hsh[wv][2 * fp + 1] = h1; }
    __syncthreads();
    float p = 0.f;
    const float* hh = hsh[wv];
#pragma unroll
    for (int f = 0; f < 32; ++f)
        p = fmaf(hh[half * 32 + f], w2[(half * 32 + f) * YD + fp], p);
    p += __shfl_xor(p, 32);
    p *= dv;
    float pn = __shfl_xor(p, 1);
    if (half == 0 && (fp & 1) == 0)
        G2h[(size_t)node * 16 + (fp >> 1)] = f2b(p) | (f2b(pn) << 16);
}

__global__ __launch_bounds__(256) void k_gather2(const int* __restrict__ rowptr,
                                                 const unsigned short* __restrict__ csr,
                                                 const unsigned* __restrict__ G2h,
                                                 const float* __restrict__ dinv,
                                                 float2* __restrict__ O2) {
    int wv = threadIdx.x >> 6, lane = threadIdx.x & 63;
    int node = blockIdx.x * 4 + wv;
    int q = lane >> 4, fp = lane & 15;
    int beg = rowptr[node], end = rowptr[node + 1];
    float ax = 0.f, ay = 0.f;
    for (int base = beg; base < end; base += 64) {
        int cnt = min(end - base, 64);
        int idx = (lane < cnt) ? (int)__builtin_nontemporal_load(csr + base + lane) : 0;
        int it = (cnt + 3) >> 2;
#pragma unroll 4
        for (int j = 0; j < it; ++j) {
            int nsel = 4 * j + q;
            int s = __shfl(idx, min(nsel, cnt - 1));
            unsigned u = G2h[(size_t)s * 16 + fp];
            float m = (nsel < cnt) ? 1.f : 0.f;
            ax = fmaf(m, blo(u), ax);
            ay = fmaf(m, bhi(u), ay);
        }
    }
    ax += __shfl_xor(ax, 16); ay += __shfl_xor(ay, 16);
    ax += __shfl_xor(ax, 32); ay += __shfl_xor(ay, 32);
    unsigned us = G2h[(size_t)node * 16 + fp];
    float dv = dinv[node];
    if (q == 0)
        O2[(size_t)node * 16 + fp] = make_float2(dv * (ax + blo(us)), dv * (ay + bhi(us)));
}

__global__ void k_out(const float* __restrict__ O2, const float* __restrict__ b2,
                      float* __restrict__ out) {
    int s = blockIdx.x * blockDim.x + threadIdx.x;
    if (s >= NS) return;
#pragma unroll
    for (int o = 0; o < YD; ++o)
        out[(size_t)o * NS + s] = O2[(size_t)s * YD + o] + b2[o];
}

// ============================================================================
extern "C" void kernel_launch(void* const* d_in, const int* in_sizes, int n_in,
                              void* d_out, int out_size, void* d_ws, size_t ws_size,
                              hipStream_t stream) {
    const float* x  = (const float*)d_in[0];
    const float* W1 = (const float*)d_in[1];
    const float* b1 = (const float*)d_in[2];
    const float* W2 = (const float*)d_in[3];
    const float* b2 = (const float*)d_in[4];
    const int* ei   = (const int*)d_in[5];
    const int* src = ei;
    const int* dst = ei + NE;

    // ---- workspace layout (4B words), same as R3 ----
    int* degi     = (int*)d_ws;            // 50000
    int* rowptr   = degi + 50000;          // 50004
    int* cursor   = rowptr + 50004;        // 50000
    int* partials = cursor + 50000;        // 256
    int* blockoff = partials + 256;        // 256
    unsigned short* csr = (unsigned short*)(blockoff + 256);   // 800000 u16
    float* dinv   = (float*)((int*)(blockoff + 256) + 400000);
    unsigned* G1h = (unsigned*)(dinv + 50000);   // 50000*32 words
    unsigned* G2h = G1h + (size_t)50000 * 32;    // 50000*16 words
    float* O2     = (float*)(G2h + (size_t)50000 * 16);  // 50000*32 floats
    float* out    = (float*)d_out;

    // cooperative single-kernel path
    void* args[] = {
        (void*)&x, (void*)&W1, (void*)&b1, (void*)&W2, (void*)&b2,
        (void*)&src, (void*)&dst, (void*)&degi, (void*)&rowptr, (void*)&cursor,
        (void*)&partials, (void*)&blockoff, (void*)&csr, (void*)&dinv,
        (void*)&G1h, (void*)&G2h, (void*)&O2, (void*)&out
    };
    hipError_t err = hipLaunchCooperativeKernel((const void*)k_all, dim3(NBLK),
                                                dim3(NTHR), args, 0, stream);
    if (err != hipSuccess) {
        // fallback: proven R3 multi-kernel sequence
        hipMemsetAsync(degi, 0, (size_t)50000 * sizeof(int), stream);
        k_degi<<<(NE + 255) / 256, 256, 0, stream>>>(dst, degi);
        k_part<<<SCAN_NBLK, 256, 0, stream>>>(degi, partials);
        k_scan2<<<1, 256, 0, stream>>>(partials, blockoff);
        k_apply<<<SCAN_NBLK, 256, 0, stream>>>(degi, blockoff, rowptr, cursor, dinv);
        k_fill<<<(NE + 255) / 256, 256, 0, stream>>>(src, dst, cursor, csr);
        k_xw1<<<(NS + 255) / 256, 256, 0, stream>>>(x, W1, dinv, G1h);
        k_g1l2<<<NS / 4, 256, 0, stream>>>(rowptr, csr, G1h, dinv, b1, W2, G2h);
        k_gather2<<<NS / 4, 256, 0, stream>>>(rowptr, csr, G2h, dinv, (float2*)O2);
        k_out<<<(NS + 255) / 256, 256, 0, stream>>>(O2, b2, out);
    }
}

// Round 6
// 180.997 us; speedup vs baseline: 5.9482x; 5.9482x over previous
//
#include <hip/hip_runtime.h>

#define NS 50000
#define NE 800000
#define XD 64
#define HD 64
#define YD 32

#define SCAN_CHUNK 256
#define SCAN_NBLK ((NS + SCAN_CHUNK - 1) / SCAN_CHUNK)  // 196

#define FILL_BLKS 416
#define XW_BLKS 196
#define MIX_BLKS (FILL_BLKS + XW_BLKS)

// ---- bf16 helpers (round-to-nearest-even pack, cheap unpack) ----
__device__ __forceinline__ unsigned f2b(float f) {
    union { float f; unsigned u; } c; c.f = f;
    return (c.u + 0x7fffu + ((c.u >> 16) & 1u)) >> 16;
}
__device__ __forceinline__ float blo(unsigned u) {
    union { unsigned u; float f; } c; c.u = u << 16; return c.f;
}
__device__ __forceinline__ float bhi(unsigned u) {
    union { unsigned u; float f; } c; c.u = u & 0xffff0000u; return c.f;
}

// ---------------- int in-degree count ----------------
__global__ void k_degi(const int* __restrict__ dst, int* __restrict__ deg) {
    int e = blockIdx.x * blockDim.x + threadIdx.x;
    if (e < NE) atomicAdd(&deg[__builtin_nontemporal_load(dst + e)], 1);
}

// ---------------- scan stage 1: per-block partial sums ----------------
__global__ __launch_bounds__(256) void k_part(const int* __restrict__ deg,
                                              int* __restrict__ partials) {
    __shared__ int red[256];
    int t = threadIdx.x;
    int i = blockIdx.x * SCAN_CHUNK + t;
    red[t] = (i < NS) ? deg[i] : 0;
    __syncthreads();
    for (int off = 128; off > 0; off >>= 1) {
        if (t < off) red[t] += red[t + off];
        __syncthreads();
    }
    if (t == 0) partials[blockIdx.x] = red[0];
}

// ---------------- scan stage 2: scan the partials (1 tiny block) ----------------
__global__ __launch_bounds__(256) void k_scan2(const int* __restrict__ partials,
                                               int* __restrict__ blockoff) {
    __shared__ int sm[256];
    int t = threadIdx.x;
    int v = (t < SCAN_NBLK) ? partials[t] : 0;
    sm[t] = v;
    __syncthreads();
    int val = v;
    for (int off = 1; off < 256; off <<= 1) {
        int other = (t >= off) ? sm[t - off] : 0;
        __syncthreads();
        val += other;
        sm[t] = val;
        __syncthreads();
    }
    if (t < SCAN_NBLK) blockoff[t] = val - v;  // exclusive
}

// ---------------- scan stage 3: intra-block scan + write rowptr/cursor/dinv ----
__global__ __launch_bounds__(256) void k_apply(const int* __restrict__ deg,
                                               const int* __restrict__ blockoff,
                                               int* __restrict__ rowptr,
                                               int* __restrict__ cursor,
                                               float* __restrict__ dinv) {
    __shared__ int sm[256];
    int t = threadIdx.x;
    int i = blockIdx.x * SCAN_CHUNK + t;
    int dg = (i < NS) ? deg[i] : 0;
    sm[t] = dg;
    __syncthreads();
    int val = dg;
    for (int off = 1; off < 256; off <<= 1) {
        int other = (t >= off) ? sm[t - off] : 0;
        __syncthreads();
        val += other;
        sm[t] = val;
        __syncthreads();
    }
    if (i < NS) {
        int ex = blockoff[blockIdx.x] + val - dg;
        rowptr[i] = ex;
        cursor[i] = ex;
        dinv[i] = rsqrtf((float)dg + 1.0f);  // +1 = self loop
    }
    if (blockIdx.x == 0 && t == 0) rowptr[NS] = NE;
}

// ---------------- merged: CSR fill (blocks < FILL_BLKS) || xw1 (rest) --------
// Independent stages, both depend only on the scan; overlapping hides fill's
// atomic latency under xw1's VALU work.
__global__ __launch_bounds__(256) void k_fillxw1(
    const int* __restrict__ src, const int* __restrict__ dst,
    int* __restrict__ cursor, unsigned short* __restrict__ csr,
    const float* __restrict__ x, const float* __restrict__ W1,
    const float* __restrict__ dinv, unsigned* __restrict__ G1h)
{
    __shared__ float w[XD * HD];
    if (blockIdx.x < FILL_BLKS) {
        int ft = blockIdx.x * 256 + threadIdx.x;
        for (int e = ft; e < NE; e += FILL_BLKS * 256) {
            int d = __builtin_nontemporal_load(dst + e);
            int s = __builtin_nontemporal_load(src + e);
            int pos = atomicAdd(&cursor[d], 1);
            csr[pos] = (unsigned short)s;
        }
        return;
    }
    for (int i = threadIdx.x; i < XD * HD; i += 256) w[i] = W1[i];
    __syncthreads();
    int s = (blockIdx.x - FILL_BLKS) * 256 + threadIdx.x;
    if (s >= NS) return;
    float4 acc[HD / 4];
#pragma unroll
    for (int i = 0; i < HD / 4; ++i) acc[i] = make_float4(0.f, 0.f, 0.f, 0.f);
    for (int xf = 0; xf < XD; ++xf) {
        float xv = __builtin_nontemporal_load(&x[(size_t)xf * NS + s]);  // coalesced
        const float4* wr = (const float4*)&w[xf * HD];
#pragma unroll
        for (int i = 0; i < HD / 4; ++i) {
            float4 wv = wr[i];
            acc[i].x += xv * wv.x; acc[i].y += xv * wv.y;
            acc[i].z += xv * wv.z; acc[i].w += xv * wv.w;
        }
    }
    float dv = dinv[s];
    unsigned pk[HD / 2];
#pragma unroll
    for (int i = 0; i < HD / 4; ++i) {
        pk[2 * i]     = f2b(dv * acc[i].x) | (f2b(dv * acc[i].y) << 16);
        pk[2 * i + 1] = f2b(dv * acc[i].z) | (f2b(dv * acc[i].w) << 16);
    }
    uint4* o = (uint4*)&G1h[(size_t)s * (HD / 2)];
#pragma unroll
    for (int i = 0; i < HD / 8; ++i) o[i] = ((uint4*)pk)[i];
}

// ---------------- fused gather-1 + ReLU + layer-2 matvec ----------------
// 4x16-lane teams per wave; each lane reads a uint2 (4 bf16 features = 8B),
// 4 neighbor rows in flight per team x unroll 4 -> ~16 outstanding rows/wave.
__global__ __launch_bounds__(256) void k_g1l2(const int* __restrict__ rowptr,
                                              const unsigned short* __restrict__ csr,
                                              const unsigned* __restrict__ G1h,
                                              const float* __restrict__ dinv,
                                              const float* __restrict__ b1,
                                              const float* __restrict__ W2,
                                              unsigned* __restrict__ G2h) {
    __shared__ float w2[HD * YD];   // 8 KB
    __shared__ float bsh[HD];
    __shared__ float hsh[4][HD];
    for (int i = threadIdx.x; i < HD * YD; i += 256) w2[i] = W2[i];
    if (threadIdx.x < HD) bsh[threadIdx.x] = b1[threadIdx.x];
    __syncthreads();
    int wv = threadIdx.x >> 6, lane = threadIdx.x & 63;
    int node = blockIdx.x * 4 + wv;
    int q = lane >> 4, fp = lane & 15;      // team 0..3, feature-quad 0..15
    int beg = rowptr[node], end = rowptr[node + 1];
    float a0 = 0.f, a1 = 0.f, a2 = 0.f, a3 = 0.f;
    for (int base = beg; base < end; base += 64) {
        int cnt = min(end - base, 64);
        int idx = (lane < cnt) ? (int)__builtin_nontemporal_load(csr + base + lane) : 0;
        int it = (cnt + 3) >> 2;
#pragma unroll 4
        for (int j = 0; j < it; ++j) {
            int nsel = 4 * j + q;
            int s = __shfl(idx, min(nsel, cnt - 1));
            uint2 u = *(const uint2*)&G1h[(size_t)s * 32 + 2 * fp];  // 8B/lane
            float m = (nsel < cnt) ? 1.f : 0.f;
            a0 = fmaf(m, blo(u.x), a0); a1 = fmaf(m, bhi(u.x), a1);
            a2 = fmaf(m, blo(u.y), a2); a3 = fmaf(m, bhi(u.y), a3);
        }
    }
    a0 += __shfl_xor(a0, 16); a1 += __shfl_xor(a1, 16);
    a2 += __shfl_xor(a2, 16); a3 += __shfl_xor(a3, 16);
    a0 += __shfl_xor(a0, 32); a1 += __shfl_xor(a1, 32);
    a2 += __shfl_xor(a2, 32); a3 += __shfl_xor(a3, 32);
    uint2 us = *(const uint2*)&G1h[(size_t)node * 32 + 2 * fp];  // self loop
    float dv = dinv[node];
    if (q == 0) {
        hsh[wv][4 * fp + 0] = fmaxf(fmaf(dv, a0 + blo(us.x), bsh[4 * fp + 0]), 0.f);
        hsh[wv][4 * fp + 1] = fmaxf(fmaf(dv, a1 + bhi(us.x), bsh[4 * fp + 1]), 0.f);
        hsh[wv][4 * fp + 2] = fmaxf(fmaf(dv, a2 + blo(us.y), bsh[4 * fp + 2]), 0.f);
        hsh[wv][4 * fp + 3] = fmaxf(fmaf(dv, a3 + bhi(us.y), bsh[4 * fp + 3]), 0.f);
    }
    __syncthreads();
    // phase 2: G2[node][o] = dv * sum_f h[f]*W2[f][o]; o = lane&31, f split by half
    int half = lane >> 5, o = lane & 31;
    float p = 0.f;
    const float* hh = hsh[wv];
#pragma unroll
    for (int f = 0; f < 32; ++f)
        p = fmaf(hh[half * 32 + f], w2[(half * 32 + f) * YD + o], p);
    p += __shfl_xor(p, 32);
    p *= dv;
    float pn = __shfl_xor(p, 1);
    if (half == 0 && (o & 1) == 0)
        G2h[(size_t)node * 16 + (o >> 1)] = f2b(p) | (f2b(pn) << 16);
}

// ---------------- gather layer 2: 8x8-lane teams per wave ----------------
__global__ __launch_bounds__(256) void k_gather2(const int* __restrict__ rowptr,
                                                 const unsigned short* __restrict__ csr,
                                                 const unsigned* __restrict__ G2h,
                                                 const float* __restrict__ dinv,
                                                 float* __restrict__ O2) {
    int wv = threadIdx.x >> 6, lane = threadIdx.x & 63;
    int node = blockIdx.x * 4 + wv;
    int q = lane >> 3, fp = lane & 7;       // team 0..7, feature-quad 0..7
    int beg = rowptr[node], end = rowptr[node + 1];
    float a0 = 0.f, a1 = 0.f, a2 = 0.f, a3 = 0.f;
    for (int base = beg; base < end; base += 64) {
        int cnt = min(end - base, 64);
        int idx = (lane < cnt) ? (int)__builtin_nontemporal_load(csr + base + lane) : 0;
        int it = (cnt + 7) >> 3;
#pragma unroll 4
        for (int j = 0; j < it; ++j) {
            int nsel = 8 * j + q;
            int s = __shfl(idx, min(nsel, cnt - 1));
            uint2 u = *(const uint2*)&G2h[(size_t)s * 16 + 2 * fp];  // 8B/lane
            float m = (nsel < cnt) ? 1.f : 0.f;
            a0 = fmaf(m, blo(u.x), a0); a1 = fmaf(m, bhi(u.x), a1);
            a2 = fmaf(m, blo(u.y), a2); a3 = fmaf(m, bhi(u.y), a3);
        }
    }
    a0 += __shfl_xor(a0, 8);  a1 += __shfl_xor(a1, 8);
    a2 += __shfl_xor(a2, 8);  a3 += __shfl_xor(a3, 8);
    a0 += __shfl_xor(a0, 16); a1 += __shfl_xor(a1, 16);
    a2 += __shfl_xor(a2, 16); a3 += __shfl_xor(a3, 16);
    a0 += __shfl_xor(a0, 32); a1 += __shfl_xor(a1, 32);
    a2 += __shfl_xor(a2, 32); a3 += __shfl_xor(a3, 32);
    uint2 us = *(const uint2*)&G2h[(size_t)node * 16 + 2 * fp];
    float dv = dinv[node];
    if (q == 0) {
        float4 r;
        r.x = dv * (a0 + blo(us.x));
        r.y = dv * (a1 + bhi(us.x));
        r.z = dv * (a2 + blo(us.y));
        r.w = dv * (a3 + bhi(us.y));
        *(float4*)&O2[(size_t)node * 32 + 4 * fp] = r;   // 16B/lane, 128B/node
    }
}

// ---------------- final epilogue + transpose ----------------
__global__ void k_out(const float* __restrict__ O2, const float* __restrict__ b2,
                      float* __restrict__ out) {
    int s = blockIdx.x * blockDim.x + threadIdx.x;
    if (s >= NS) return;
#pragma unroll
    for (int o = 0; o < YD; ++o)
        out[(size_t)o * NS + s] = O2[(size_t)s * YD + o] + b2[o];  // coalesced over s
}

extern "C" void kernel_launch(void* const* d_in, const int* in_sizes, int n_in,
                              void* d_out, int out_size, void* d_ws, size_t ws_size,
                              hipStream_t stream) {
    const float* x  = (const float*)d_in[0];
    const float* W1 = (const float*)d_in[1];
    const float* b1 = (const float*)d_in[2];
    const float* W2 = (const float*)d_in[3];
    const float* b2 = (const float*)d_in[4];
    const int* ei   = (const int*)d_in[5];
    const int* src = ei;
    const int* dst = ei + NE;

    // ---- workspace layout (4B words) ----
    int* degi     = (int*)d_ws;            // 50000
    int* rowptr   = degi + 50000;          // 50004
    int* cursor   = rowptr + 50004;        // 50000
    int* partials = cursor + 50000;        // 256
    int* blockoff = partials + 256;        // 256
    unsigned short* csr = (unsigned short*)(blockoff + 256);   // 800000 u16
    float* dinv   = (float*)((int*)(blockoff + 256) + 400000);
    unsigned* G1h = (unsigned*)(dinv + 50000);   // 50000*32 words (bf16 pairs)
    unsigned* G2h = G1h + (size_t)50000 * 32;    // 50000*16 words
    float* O2     = (float*)(G2h + (size_t)50000 * 16);  // 50000*32 floats
    float* out    = (float*)d_out;

    hipMemsetAsync(degi, 0, (size_t)50000 * sizeof(int), stream);

    k_degi<<<(NE + 255) / 256, 256, 0, stream>>>(dst, degi);
    k_part<<<SCAN_NBLK, 256, 0, stream>>>(degi, partials);
    k_scan2<<<1, 256, 0, stream>>>(partials, blockoff);
    k_apply<<<SCAN_NBLK, 256, 0, stream>>>(degi, blockoff, rowptr, cursor, dinv);
    k_fillxw1<<<MIX_BLKS, 256, 0, stream>>>(src, dst, cursor, csr, x, W1, dinv, G1h);
    k_g1l2<<<NS / 4, 256, 0, stream>>>(rowptr, csr, G1h, dinv, b1, W2, G2h);
    k_gather2<<<NS / 4, 256, 0, stream>>>(rowptr, csr, G2h, dinv, O2);
    k_out<<<(NS + 255) / 256, 256, 0, stream>>>(O2, b2, out);
}

// Round 7
// 129.595 us; speedup vs baseline: 8.3074x; 1.3966x over previous
//
#include <hip/hip_runtime.h>

#define NS 50000
#define NE 800000
#define XD 64
#define HD 64
#define YD 32

#define SHIFT 7
#define BNODES 128                       // nodes per bucket
#define NBUCK 391                        // ceil(NS / BNODES)
#define BCAP 2560                        // edge capacity per bucket (exp 2046, sigma ~45)
#define NBLKA 256
#define EPB ((NE + NBLKA - 1) / NBLKA)   // 3125 edges per pass-A block

// ---- bf16 helpers (round-to-nearest-even pack, cheap unpack) ----
__device__ __forceinline__ unsigned f2b(float f) {
    union { float f; unsigned u; } c; c.f = f;
    return (c.u + 0x7fffu + ((c.u >> 16) & 1u)) >> 16;
}
__device__ __forceinline__ float blo(unsigned u) {
    union { unsigned u; float f; } c; c.u = u << 16; return c.f;
}
__device__ __forceinline__ float bhi(unsigned u) {
    union { unsigned u; float f; } c; c.u = u & 0xffff0000u; return c.f;
}

// ---------------- pass A: bucket edges by dst>>SHIFT (fixed-capacity regions) --
__global__ __launch_bounds__(256) void k_bucket(const int* __restrict__ src,
                                                const int* __restrict__ dst,
                                                int* __restrict__ bcur,
                                                unsigned* __restrict__ ebuf) {
    __shared__ int hist[NBUCK];
    __shared__ int base[NBUCK];
    int t = threadIdx.x;
    int lo = blockIdx.x * EPB;
    int hi = min(lo + EPB, NE);
    for (int i = t; i < NBUCK; i += 256) hist[i] = 0;
    __syncthreads();
    for (int e = lo + t; e < hi; e += 256)
        atomicAdd(&hist[((unsigned)__builtin_nontemporal_load(dst + e)) >> SHIFT], 1);
    __syncthreads();
    for (int i = t; i < NBUCK; i += 256) {
        int c = hist[i];
        base[i] = c ? atomicAdd(&bcur[i], c) : 0;  // reserve slice in bucket region
        hist[i] = 0;                               // reuse as local cursor
    }
    __syncthreads();
    for (int e = lo + t; e < hi; e += 256) {
        unsigned d = (unsigned)__builtin_nontemporal_load(dst + e);
        unsigned s = (unsigned)__builtin_nontemporal_load(src + e);
        int b = d >> SHIFT;
        int pos = base[b] + atomicAdd(&hist[b], 1);
        if (pos < BCAP) ebuf[(size_t)b * BCAP + pos] = (d << 16) | s;  // never drops (11+ sigma)
    }
}

// ---------------- pass B: per-bucket exact sort + beg/end/dinv + xw1 tail -----
__global__ __launch_bounds__(256) void k_sortxw1(const unsigned* __restrict__ ebuf,
                                                 const int* __restrict__ bcur,
                                                 unsigned short* __restrict__ csr,
                                                 int* __restrict__ beg,
                                                 int* __restrict__ endp,
                                                 float* __restrict__ dinv,
                                                 const float* __restrict__ x,
                                                 const float* __restrict__ W1,
                                                 unsigned* __restrict__ G1h) {
    __shared__ float w1[XD * HD];          // 16 KB
    __shared__ unsigned se[BCAP];          // 10 KB staged edges
    __shared__ unsigned short lcsr[BCAP];  // 5 KB  sorted src ids
    __shared__ int cnt[BNODES];
    __shared__ int offl[BNODES];
    __shared__ int cur[BNODES];
    __shared__ int sm[256];
    int b = blockIdx.x, t = threadIdx.x;
    for (int i = t; i < XD * HD; i += 256) w1[i] = W1[i];
    int n = min(bcur[b], BCAP);
    const unsigned* eb = ebuf + (size_t)b * BCAP;
    for (int i = t; i < n; i += 256) se[i] = eb[i];
    if (t < BNODES) cnt[t] = 0;
    __syncthreads();
    // per-node degree count (local node id = dst & 127)
    for (int i = t; i < n; i += 256) atomicAdd(&cnt[(se[i] >> 16) & (BNODES - 1)], 1);
    __syncthreads();
    // exclusive scan of cnt[128]
    int v = (t < BNODES) ? cnt[t] : 0;
    sm[t] = v;
    __syncthreads();
    int val = v;
    for (int o = 1; o < BNODES; o <<= 1) {
        int other = (t >= o) ? sm[t - o] : 0;
        __syncthreads();
        val += other;
        sm[t] = val;
        __syncthreads();
    }
    if (t < BNODES) { offl[t] = val - v; cur[t] = val - v; }
    __syncthreads();
    // place src ids
    for (int i = t; i < n; i += 256) {
        unsigned p = se[i];
        int l = (p >> 16) & (BNODES - 1);
        int pos = atomicAdd(&cur[l], 1);
        lcsr[pos] = (unsigned short)(p & 0xffffu);
    }
    __syncthreads();
    // flush csr coalesced (u32 pairs)
    unsigned* gc = (unsigned*)(csr + (size_t)b * BCAP);
    int nw = (n + 1) >> 1;
    for (int i = t; i < nw; i += 256) gc[i] = ((const unsigned*)lcsr)[i];
    // per-node metadata
    if (t < BNODES) {
        int node = b * BNODES + t;
        if (node < NS) {
            int bg = b * BCAP + offl[t];
            beg[node] = bg;
            endp[node] = bg + cnt[t];
            dinv[node] = rsqrtf((float)cnt[t] + 1.0f);  // +1 = self loop
        }
    }
    // ---- xw1 tail: G1[node][f] = dinv*sum_xf x[xf][node]*W1[xf][f] ----
    // feature-split: threads t<128 do features 0..31 of node t, t>=128 do 32..63
    int half = t >> 7, tn = t & (BNODES - 1);
    int node = b * BNODES + tn;
    if (node >= NS) return;
    float4 acc[8];
#pragma unroll
    for (int i = 0; i < 8; ++i) acc[i] = make_float4(0.f, 0.f, 0.f, 0.f);
    for (int xf = 0; xf < XD; ++xf) {
        float xv = __builtin_nontemporal_load(&x[(size_t)xf * NS + node]);  // coalesced
        const float4* wr = (const float4*)&w1[xf * HD + half * 32];
#pragma unroll
        for (int i = 0; i < 8; ++i) {
            float4 wv = wr[i];
            acc[i].x += xv * wv.x; acc[i].y += xv * wv.y;
            acc[i].z += xv * wv.z; acc[i].w += xv * wv.w;
        }
    }
    float dv = rsqrtf((float)cnt[tn] + 1.0f);
    unsigned pk[16];
#pragma unroll
    for (int i = 0; i < 8; ++i) {
        pk[2 * i]     = f2b(dv * acc[i].x) | (f2b(dv * acc[i].y) << 16);
        pk[2 * i + 1] = f2b(dv * acc[i].z) | (f2b(dv * acc[i].w) << 16);
    }
    uint4* o = (uint4*)&G1h[(size_t)node * 32 + half * 16];
#pragma unroll
    for (int i = 0; i < 4; ++i) o[i] = ((uint4*)pk)[i];
}

// ---------------- fused gather-1 + ReLU + layer-2 matvec ----------------
// 4x16-lane teams per wave; uint2 (4 bf16 features = 8B) per lane.
__global__ __launch_bounds__(256) void k_g1l2(const int* __restrict__ beg,
                                              const int* __restrict__ endp,
                                              const unsigned short* __restrict__ csr,
                                              const unsigned* __restrict__ G1h,
                                              const float* __restrict__ dinv,
                                              const float* __restrict__ b1,
                                              const float* __restrict__ W2,
                                              unsigned* __restrict__ G2h) {
    __shared__ float w2[HD * YD];   // 8 KB
    __shared__ float bsh[HD];
    __shared__ float hsh[4][HD];
    for (int i = threadIdx.x; i < HD * YD; i += 256) w2[i] = W2[i];
    if (threadIdx.x < HD) bsh[threadIdx.x] = b1[threadIdx.x];
    __syncthreads();
    int wv = threadIdx.x >> 6, lane = threadIdx.x & 63;
    int node = blockIdx.x * 4 + wv;
    int q = lane >> 4, fp = lane & 15;      // team 0..3, feature-quad 0..15
    int beg_ = beg[node], end_ = endp[node];
    float a0 = 0.f, a1 = 0.f, a2 = 0.f, a3 = 0.f;
    for (int base = beg_; base < end_; base += 64) {
        int cnt = min(end_ - base, 64);
        int idx = (lane < cnt) ? (int)__builtin_nontemporal_load(csr + base + lane) : 0;
        int it = (cnt + 3) >> 2;
#pragma unroll 4
        for (int j = 0; j < it; ++j) {
            int nsel = 4 * j + q;
            int s = __shfl(idx, min(nsel, cnt - 1));
            uint2 u = *(const uint2*)&G1h[(size_t)s * 32 + 2 * fp];  // 8B/lane
            float m = (nsel < cnt) ? 1.f : 0.f;
            a0 = fmaf(m, blo(u.x), a0); a1 = fmaf(m, bhi(u.x), a1);
            a2 = fmaf(m, blo(u.y), a2); a3 = fmaf(m, bhi(u.y), a3);
        }
    }
    a0 += __shfl_xor(a0, 16); a1 += __shfl_xor(a1, 16);
    a2 += __shfl_xor(a2, 16); a3 += __shfl_xor(a3, 16);
    a0 += __shfl_xor(a0, 32); a1 += __shfl_xor(a1, 32);
    a2 += __shfl_xor(a2, 32); a3 += __shfl_xor(a3, 32);
    uint2 us = *(const uint2*)&G1h[(size_t)node * 32 + 2 * fp];  // self loop
    float dv = dinv[node];
    if (q == 0) {
        hsh[wv][4 * fp + 0] = fmaxf(fmaf(dv, a0 + blo(us.x), bsh[4 * fp + 0]), 0.f);
        hsh[wv][4 * fp + 1] = fmaxf(fmaf(dv, a1 + bhi(us.x), bsh[4 * fp + 1]), 0.f);
        hsh[wv][4 * fp + 2] = fmaxf(fmaf(dv, a2 + blo(us.y), bsh[4 * fp + 2]), 0.f);
        hsh[wv][4 * fp + 3] = fmaxf(fmaf(dv, a3 + bhi(us.y), bsh[4 * fp + 3]), 0.f);
    }
    __syncthreads();
    // phase 2: G2[node][o] = dv * sum_f h[f]*W2[f][o]
    int half = lane >> 5, o = lane & 31;
    float p = 0.f;
    const float* hh = hsh[wv];
#pragma unroll
    for (int f = 0; f < 32; ++f)
        p = fmaf(hh[half * 32 + f], w2[(half * 32 + f) * YD + o], p);
    p += __shfl_xor(p, 32);
    p *= dv;
    float pn = __shfl_xor(p, 1);
    if (half == 0 && (o & 1) == 0)
        G2h[(size_t)node * 16 + (o >> 1)] = f2b(p) | (f2b(pn) << 16);
}

// ---------------- gather layer 2: 8x8-lane teams per wave ----------------
__global__ __launch_bounds__(256) void k_gather2(const int* __restrict__ beg,
                                                 const int* __restrict__ endp,
                                                 const unsigned short* __restrict__ csr,
                                                 const unsigned* __restrict__ G2h,
                                                 const float* __restrict__ dinv,
                                                 float* __restrict__ O2) {
    int wv = threadIdx.x >> 6, lane = threadIdx.x & 63;
    int node = blockIdx.x * 4 + wv;
    int q = lane >> 3, fp = lane & 7;       // team 0..7, feature-quad 0..7
    int beg_ = beg[node], end_ = endp[node];
    float a0 = 0.f, a1 = 0.f, a2 = 0.f, a3 = 0.f;
    for (int base = beg_; base < end_; base += 64) {
        int cnt = min(end_ - base, 64);
        int idx = (lane < cnt) ? (int)__builtin_nontemporal_load(csr + base + lane) : 0;
        int it = (cnt + 7) >> 3;
#pragma unroll 4
        for (int j = 0; j < it; ++j) {
            int nsel = 8 * j + q;
            int s = __shfl(idx, min(nsel, cnt - 1));
            uint2 u = *(const uint2*)&G2h[(size_t)s * 16 + 2 * fp];  // 8B/lane
            float m = (nsel < cnt) ? 1.f : 0.f;
            a0 = fmaf(m, blo(u.x), a0); a1 = fmaf(m, bhi(u.x), a1);
            a2 = fmaf(m, blo(u.y), a2); a3 = fmaf(m, bhi(u.y), a3);
        }
    }
    a0 += __shfl_xor(a0, 8);  a1 += __shfl_xor(a1, 8);
    a2 += __shfl_xor(a2, 8);  a3 += __shfl_xor(a3, 8);
    a0 += __shfl_xor(a0, 16); a1 += __shfl_xor(a1, 16);
    a2 += __shfl_xor(a2, 16); a3 += __shfl_xor(a3, 16);
    a0 += __shfl_xor(a0, 32); a1 += __shfl_xor(a1, 32);
    a2 += __shfl_xor(a2, 32); a3 += __shfl_xor(a3, 32);
    uint2 us = *(const uint2*)&G2h[(size_t)node * 16 + 2 * fp];
    float dv = dinv[node];
    if (q == 0) {
        float4 r;
        r.x = dv * (a0 + blo(us.x));
        r.y = dv * (a1 + bhi(us.x));
        r.z = dv * (a2 + blo(us.y));
        r.w = dv * (a3 + bhi(us.y));
        *(float4*)&O2[(size_t)node * 32 + 4 * fp] = r;
    }
}

// ---------------- final epilogue + transpose ----------------
__global__ void k_out(const float* __restrict__ O2, const float* __restrict__ b2,
                      float* __restrict__ out) {
    int s = blockIdx.x * blockDim.x + threadIdx.x;
    if (s >= NS) return;
#pragma unroll
    for (int o = 0; o < YD; ++o)
        out[(size_t)o * NS + s] = O2[(size_t)s * YD + o] + b2[o];  // coalesced over s
}

extern "C" void kernel_launch(void* const* d_in, const int* in_sizes, int n_in,
                              void* d_out, int out_size, void* d_ws, size_t ws_size,
                              hipStream_t stream) {
    const float* x  = (const float*)d_in[0];
    const float* W1 = (const float*)d_in[1];
    const float* b1 = (const float*)d_in[2];
    const float* W2 = (const float*)d_in[3];
    const float* b2 = (const float*)d_in[4];
    const int* ei   = (const int*)d_in[5];
    const int* src = ei;
    const int* dst = ei + NE;

    // ---- workspace layout (4B words) ----
    int* bcur     = (int*)d_ws;                               // 391 (pad 512)
    unsigned* ebuf = (unsigned*)(bcur + 512);                 // NBUCK*BCAP = 1000960
    unsigned short* csr = (unsigned short*)(ebuf + (size_t)NBUCK * BCAP);  // 500480 words
    int* beg      = (int*)((unsigned*)csr + (size_t)NBUCK * BCAP / 2);     // 50000
    int* endp     = beg + 50000;                              // 50000
    float* dinv   = (float*)(endp + 50000);                   // 50000
    unsigned* G1h = (unsigned*)(dinv + 50000);                // 50000*32
    unsigned* G2h = G1h + (size_t)50000 * 32;                 // 50000*16
    float* O2     = (float*)(G2h + (size_t)50000 * 16);       // 50000*32
    float* out    = (float*)d_out;

    hipMemsetAsync(bcur, 0, NBUCK * sizeof(int), stream);

    k_bucket<<<NBLKA, 256, 0, stream>>>(src, dst, bcur, ebuf);
    k_sortxw1<<<NBUCK, 256, 0, stream>>>(ebuf, bcur, csr, beg, endp, dinv, x, W1, G1h);
    k_g1l2<<<NS / 4, 256, 0, stream>>>(beg, endp, csr, G1h, dinv, b1, W2, G2h);
    k_gather2<<<NS / 4, 256, 0, stream>>>(beg, endp, csr, G2h, dinv, O2);
    k_out<<<(NS + 255) / 256, 256, 0, stream>>>(O2, b2, out);
}

// Round 8
// 126.526 us; speedup vs baseline: 8.5089x; 1.0243x over previous
//
#include <hip/hip_runtime.h>

#define NS 50000
#define NE 800000
#define XD 64
#define HD 64
#define YD 32

#define SHIFT 7
#define BNODES 128                       // nodes per bucket
#define NBUCK 391                        // ceil(NS / BNODES)
#define BCAP 2560                        // edge capacity per bucket (exp 2046, sigma ~45)
#define NBLKA 256
#define EPB ((NE + NBLKA - 1) / NBLKA)   // 3125 edges per pass-A block

// ---- bf16 helpers (round-to-nearest-even pack, cheap unpack) ----
__device__ __forceinline__ unsigned f2b(float f) {
    union { float f; unsigned u; } c; c.f = f;
    return (c.u + 0x7fffu + ((c.u >> 16) & 1u)) >> 16;
}
__device__ __forceinline__ float blo(unsigned u) {
    union { unsigned u; float f; } c; c.u = u << 16; return c.f;
}
__device__ __forceinline__ float bhi(unsigned u) {
    union { unsigned u; float f; } c; c.u = u & 0xffff0000u; return c.f;
}

// ---------------- tiny zero (replaces 45us fillBufferAligned dispatch) -------
__global__ void k_zero(int* __restrict__ bcur) {
    int t = threadIdx.x;
    if (t < NBUCK) bcur[t] = 0;
}

// ---------------- pass A: bucket edges by dst>>SHIFT (fixed-capacity regions) --
__global__ __launch_bounds__(256) void k_bucket(const int* __restrict__ src,
                                                const int* __restrict__ dst,
                                                int* __restrict__ bcur,
                                                unsigned* __restrict__ ebuf) {
    __shared__ int hist[NBUCK];
    __shared__ int base[NBUCK];
    int t = threadIdx.x;
    int lo = blockIdx.x * EPB;
    int hi = min(lo + EPB, NE);
    for (int i = t; i < NBUCK; i += 256) hist[i] = 0;
    __syncthreads();
    for (int e = lo + t; e < hi; e += 256)
        atomicAdd(&hist[((unsigned)__builtin_nontemporal_load(dst + e)) >> SHIFT], 1);
    __syncthreads();
    for (int i = t; i < NBUCK; i += 256) {
        int c = hist[i];
        base[i] = c ? atomicAdd(&bcur[i], c) : 0;  // reserve slice in bucket region
        hist[i] = 0;                               // reuse as local cursor
    }
    __syncthreads();
    for (int e = lo + t; e < hi; e += 256) {
        unsigned d = (unsigned)__builtin_nontemporal_load(dst + e);
        unsigned s = (unsigned)__builtin_nontemporal_load(src + e);
        int b = d >> SHIFT;
        int pos = base[b] + atomicAdd(&hist[b], 1);
        if (pos < BCAP) ebuf[(size_t)b * BCAP + pos] = (d << 16) | s;  // never drops (11+ sigma)
    }
}

// ---------------- pass B: per-bucket exact sort + beg/end/dinv + xw1 tail -----
__global__ __launch_bounds__(256) void k_sortxw1(const unsigned* __restrict__ ebuf,
                                                 const int* __restrict__ bcur,
                                                 unsigned short* __restrict__ csr,
                                                 int* __restrict__ beg,
                                                 int* __restrict__ endp,
                                                 float* __restrict__ dinv,
                                                 const float* __restrict__ x,
                                                 const float* __restrict__ W1,
                                                 unsigned* __restrict__ G1h) {
    __shared__ float w1[XD * HD];          // 16 KB
    __shared__ unsigned se[BCAP];          // 10 KB staged edges
    __shared__ unsigned short lcsr[BCAP];  // 5 KB  sorted src ids
    __shared__ int cnt[BNODES];
    __shared__ int offl[BNODES];
    __shared__ int cur[BNODES];
    __shared__ int sm[256];
    int b = blockIdx.x, t = threadIdx.x;
    for (int i = t; i < XD * HD; i += 256) w1[i] = W1[i];
    int n = min(bcur[b], BCAP);
    const unsigned* eb = ebuf + (size_t)b * BCAP;
    for (int i = t; i < n; i += 256) se[i] = eb[i];
    if (t < BNODES) cnt[t] = 0;
    __syncthreads();
    // per-node degree count (local node id = dst & 127)
    for (int i = t; i < n; i += 256) atomicAdd(&cnt[(se[i] >> 16) & (BNODES - 1)], 1);
    __syncthreads();
    // exclusive scan of cnt[128]
    int v = (t < BNODES) ? cnt[t] : 0;
    sm[t] = v;
    __syncthreads();
    int val = v;
    for (int o = 1; o < BNODES; o <<= 1) {
        int other = (t >= o) ? sm[t - o] : 0;
        __syncthreads();
        val += other;
        sm[t] = val;
        __syncthreads();
    }
    if (t < BNODES) { offl[t] = val - v; cur[t] = val - v; }
    __syncthreads();
    // place src ids
    for (int i = t; i < n; i += 256) {
        unsigned p = se[i];
        int l = (p >> 16) & (BNODES - 1);
        int pos = atomicAdd(&cur[l], 1);
        lcsr[pos] = (unsigned short)(p & 0xffffu);
    }
    __syncthreads();
    // flush csr coalesced (u32 pairs)
    unsigned* gc = (unsigned*)(csr + (size_t)b * BCAP);
    int nw = (n + 1) >> 1;
    for (int i = t; i < nw; i += 256) gc[i] = ((const unsigned*)lcsr)[i];
    // per-node metadata
    if (t < BNODES) {
        int node = b * BNODES + t;
        if (node < NS) {
            int bg = b * BCAP + offl[t];
            beg[node] = bg;
            endp[node] = bg + cnt[t];
            dinv[node] = rsqrtf((float)cnt[t] + 1.0f);  // +1 = self loop
        }
    }
    // ---- xw1 tail: G1[node][f] = dinv*sum_xf x[xf][node]*W1[xf][f] ----
    // feature-split: threads t<128 do features 0..31 of node t, t>=128 do 32..63
    int half = t >> 7, tn = t & (BNODES - 1);
    int node = b * BNODES + tn;
    if (node >= NS) return;
    float4 acc[8];
#pragma unroll
    for (int i = 0; i < 8; ++i) acc[i] = make_float4(0.f, 0.f, 0.f, 0.f);
    for (int xf = 0; xf < XD; ++xf) {
        float xv = __builtin_nontemporal_load(&x[(size_t)xf * NS + node]);  // coalesced
        const float4* wr = (const float4*)&w1[xf * HD + half * 32];
#pragma unroll
        for (int i = 0; i < 8; ++i) {
            float4 wv = wr[i];
            acc[i].x += xv * wv.x; acc[i].y += xv * wv.y;
            acc[i].z += xv * wv.z; acc[i].w += xv * wv.w;
        }
    }
    float dv = rsqrtf((float)cnt[tn] + 1.0f);
    unsigned pk[16];
#pragma unroll
    for (int i = 0; i < 8; ++i) {
        pk[2 * i]     = f2b(dv * acc[i].x) | (f2b(dv * acc[i].y) << 16);
        pk[2 * i + 1] = f2b(dv * acc[i].z) | (f2b(dv * acc[i].w) << 16);
    }
    uint4* o = (uint4*)&G1h[(size_t)node * 32 + half * 16];
#pragma unroll
    for (int i = 0; i < 4; ++i) o[i] = ((uint4*)pk)[i];
}

// ---------------- fused gather-1 + ReLU + layer-2 matvec ----------------
// 8x8-lane teams per wave; each lane reads uint4 (8 bf16 = 16B) -> one 128B row
// per team, 8 teams x unroll 4 = 32 neighbor rows in flight per wave.
__global__ __launch_bounds__(256) void k_g1l2(const int* __restrict__ beg,
                                              const int* __restrict__ endp,
                                              const unsigned short* __restrict__ csr,
                                              const unsigned* __restrict__ G1h,
                                              const float* __restrict__ dinv,
                                              const float* __restrict__ b1,
                                              const float* __restrict__ W2,
                                              unsigned* __restrict__ G2h) {
    __shared__ float w2[HD * YD];   // 8 KB
    __shared__ float bsh[HD];
    __shared__ float hsh[4][HD];
    for (int i = threadIdx.x; i < HD * YD; i += 256) w2[i] = W2[i];
    if (threadIdx.x < HD) bsh[threadIdx.x] = b1[threadIdx.x];
    __syncthreads();
    int wv = threadIdx.x >> 6, lane = threadIdx.x & 63;
    int node = blockIdx.x * 4 + wv;
    int q = lane >> 3, fp = lane & 7;       // team 0..7, feature-octet 0..7
    int beg_ = beg[node], end_ = endp[node];
    float a0 = 0.f, a1 = 0.f, a2 = 0.f, a3 = 0.f;
    float a4 = 0.f, a5 = 0.f, a6 = 0.f, a7 = 0.f;
    for (int base = beg_; base < end_; base += 64) {
        int cnt = min(end_ - base, 64);
        int idx = (lane < cnt) ? (int)__builtin_nontemporal_load(csr + base + lane) : 0;
        int it = (cnt + 7) >> 3;
#pragma unroll 4
        for (int j = 0; j < it; ++j) {
            int nsel = 8 * j + q;
            int s = __shfl(idx, min(nsel, cnt - 1));
            uint4 u = *(const uint4*)&G1h[(size_t)s * 32 + 4 * fp];  // 16B/lane
            float m = (nsel < cnt) ? 1.f : 0.f;
            a0 = fmaf(m, blo(u.x), a0); a1 = fmaf(m, bhi(u.x), a1);
            a2 = fmaf(m, blo(u.y), a2); a3 = fmaf(m, bhi(u.y), a3);
            a4 = fmaf(m, blo(u.z), a4); a5 = fmaf(m, bhi(u.z), a5);
            a6 = fmaf(m, blo(u.w), a6); a7 = fmaf(m, bhi(u.w), a7);
        }
    }
#pragma unroll
    for (int d = 8; d <= 32; d <<= 1) {
        a0 += __shfl_xor(a0, d); a1 += __shfl_xor(a1, d);
        a2 += __shfl_xor(a2, d); a3 += __shfl_xor(a3, d);
        a4 += __shfl_xor(a4, d); a5 += __shfl_xor(a5, d);
        a6 += __shfl_xor(a6, d); a7 += __shfl_xor(a7, d);
    }
    uint4 us = *(const uint4*)&G1h[(size_t)node * 32 + 4 * fp];  // self loop
    float dv = dinv[node];
    if (q == 0) {
        hsh[wv][8 * fp + 0] = fmaxf(fmaf(dv, a0 + blo(us.x), bsh[8 * fp + 0]), 0.f);
        hsh[wv][8 * fp + 1] = fmaxf(fmaf(dv, a1 + bhi(us.x), bsh[8 * fp + 1]), 0.f);
        hsh[wv][8 * fp + 2] = fmaxf(fmaf(dv, a2 + blo(us.y), bsh[8 * fp + 2]), 0.f);
        hsh[wv][8 * fp + 3] = fmaxf(fmaf(dv, a3 + bhi(us.y), bsh[8 * fp + 3]), 0.f);
        hsh[wv][8 * fp + 4] = fmaxf(fmaf(dv, a4 + blo(us.z), bsh[8 * fp + 4]), 0.f);
        hsh[wv][8 * fp + 5] = fmaxf(fmaf(dv, a5 + bhi(us.z), bsh[8 * fp + 5]), 0.f);
        hsh[wv][8 * fp + 6] = fmaxf(fmaf(dv, a6 + blo(us.w), bsh[8 * fp + 6]), 0.f);
        hsh[wv][8 * fp + 7] = fmaxf(fmaf(dv, a7 + bhi(us.w), bsh[8 * fp + 7]), 0.f);
    }
    __syncthreads();
    // phase 2: G2[node][o] = dv * sum_f h[f]*W2[f][o]
    int half = lane >> 5, o = lane & 31;
    float p = 0.f;
    const float* hh = hsh[wv];
#pragma unroll
    for (int f = 0; f < 32; ++f)
        p = fmaf(hh[half * 32 + f], w2[(half * 32 + f) * YD + o], p);
    p += __shfl_xor(p, 32);
    p *= dv;
    float pn = __shfl_xor(p, 1);
    if (half == 0 && (o & 1) == 0)
        G2h[(size_t)node * 16 + (o >> 1)] = f2b(p) | (f2b(pn) << 16);
}

// ---------------- gather layer 2: 8x8-lane teams per wave ----------------
__global__ __launch_bounds__(256) void k_gather2(const int* __restrict__ beg,
                                                 const int* __restrict__ endp,
                                                 const unsigned short* __restrict__ csr,
                                                 const unsigned* __restrict__ G2h,
                                                 const float* __restrict__ dinv,
                                                 float* __restrict__ O2) {
    int wv = threadIdx.x >> 6, lane = threadIdx.x & 63;
    int node = blockIdx.x * 4 + wv;
    int q = lane >> 3, fp = lane & 7;       // team 0..7, feature-quad 0..7
    int beg_ = beg[node], end_ = endp[node];
    float a0 = 0.f, a1 = 0.f, a2 = 0.f, a3 = 0.f;
    for (int base = beg_; base < end_; base += 64) {
        int cnt = min(end_ - base, 64);
        int idx = (lane < cnt) ? (int)__builtin_nontemporal_load(csr + base + lane) : 0;
        int it = (cnt + 7) >> 3;
#pragma unroll 4
        for (int j = 0; j < it; ++j) {
            int nsel = 8 * j + q;
            int s = __shfl(idx, min(nsel, cnt - 1));
            uint2 u = *(const uint2*)&G2h[(size_t)s * 16 + 2 * fp];  // 8B/lane
            float m = (nsel < cnt) ? 1.f : 0.f;
            a0 = fmaf(m, blo(u.x), a0); a1 = fmaf(m, bhi(u.x), a1);
            a2 = fmaf(m, blo(u.y), a2); a3 = fmaf(m, bhi(u.y), a3);
        }
    }
    a0 += __shfl_xor(a0, 8);  a1 += __shfl_xor(a1, 8);
    a2 += __shfl_xor(a2, 8);  a3 += __shfl_xor(a3, 8);
    a0 += __shfl_xor(a0, 16); a1 += __shfl_xor(a1, 16);
    a2 += __shfl_xor(a2, 16); a3 += __shfl_xor(a3, 16);
    a0 += __shfl_xor(a0, 32); a1 += __shfl_xor(a1, 32);
    a2 += __shfl_xor(a2, 32); a3 += __shfl_xor(a3, 32);
    uint2 us = *(const uint2*)&G2h[(size_t)node * 16 + 2 * fp];
    float dv = dinv[node];
    if (q == 0) {
        float4 r;
        r.x = dv * (a0 + blo(us.x));
        r.y = dv * (a1 + bhi(us.x));
        r.z = dv * (a2 + blo(us.y));
        r.w = dv * (a3 + bhi(us.y));
        *(float4*)&O2[(size_t)node * 32 + 4 * fp] = r;
    }
}

// ---------------- final epilogue + transpose ----------------
__global__ void k_out(const float* __restrict__ O2, const float* __restrict__ b2,
                      float* __restrict__ out) {
    int s = blockIdx.x * blockDim.x + threadIdx.x;
    if (s >= NS) return;
#pragma unroll
    for (int o = 0; o < YD; ++o)
        out[(size_t)o * NS + s] = O2[(size_t)s * YD + o] + b2[o];  // coalesced over s
}

extern "C" void kernel_launch(void* const* d_in, const int* in_sizes, int n_in,
                              void* d_out, int out_size, void* d_ws, size_t ws_size,
                              hipStream_t stream) {
    const float* x  = (const float*)d_in[0];
    const float* W1 = (const float*)d_in[1];
    const float* b1 = (const float*)d_in[2];
    const float* W2 = (const float*)d_in[3];
    const float* b2 = (const float*)d_in[4];
    const int* ei   = (const int*)d_in[5];
    const int* src = ei;
    const int* dst = ei + NE;

    // ---- workspace layout (4B words) ----
    int* bcur     = (int*)d_ws;                               // 391 (pad 512)
    unsigned* ebuf = (unsigned*)(bcur + 512);                 // NBUCK*BCAP = 1000960
    unsigned short* csr = (unsigned short*)(ebuf + (size_t)NBUCK * BCAP);  // 500480 words
    int* beg      = (int*)((unsigned*)csr + (size_t)NBUCK * BCAP / 2);     // 50000
    int* endp     = beg + 50000;                              // 50000
    float* dinv   = (float*)(endp + 50000);                   // 50000
    unsigned* G1h = (unsigned*)(dinv + 50000);                // 50000*32
    unsigned* G2h = G1h + (size_t)50000 * 32;                 // 50000*16
    float* O2     = (float*)(G2h + (size_t)50000 * 16);       // 50000*32
    float* out    = (float*)d_out;

    k_zero<<<1, 512, 0, stream>>>(bcur);
    k_bucket<<<NBLKA, 256, 0, stream>>>(src, dst, bcur, ebuf);
    k_sortxw1<<<NBUCK, 256, 0, stream>>>(ebuf, bcur, csr, beg, endp, dinv, x, W1, G1h);
    k_g1l2<<<NS / 4, 256, 0, stream>>>(beg, endp, csr, G1h, dinv, b1, W2, G2h);
    k_gather2<<<NS / 4, 256, 0, stream>>>(beg, endp, csr, G2h, dinv, O2);
    k_out<<<(NS + 255) / 256, 256, 0, stream>>>(O2, b2, out);
}